// Round 2
// baseline (8135.799 us; speedup 1.0000x reference)
//
#include <hip/hip_runtime.h>
#include <cstdint>
#include <cstddef>

#define D_DIM 256
#define E_DIM 512
#define S_DIM 128
#define B_DIM 1024
#define T_SEQ 133
#define N_UV 1152
#define NTOK (B_DIM * T_SEQ)
#define CB 64
#define MROWS (CB * T_SEQ)   // 8512 = 133*64
#define EPSF 1e-5f
#define RSQRT_S 0.08838834764831845f

typedef __attribute__((ext_vector_type(8))) short short8;
typedef __attribute__((ext_vector_type(4))) float floatx4;
#define MFMA16(a, b, c) __builtin_amdgcn_mfma_f32_16x16x32_bf16((a), (b), (c), 0, 0, 0)

__device__ __forceinline__ unsigned short f2bf(float f) {
    union { float f; unsigned u; } a; a.f = f;
    unsigned r = a.u + 0x7fffu + ((a.u >> 16) & 1u);
    return (unsigned short)(r >> 16);
}
__device__ __forceinline__ float bf2f(unsigned short h) {
    union { unsigned u; float f; } a; a.u = ((unsigned)h) << 16;
    return a.f;
}

// ---------------------------------------------------------------------------
// Cast weights to bf16 once per launch.
// ---------------------------------------------------------------------------
__global__ __launch_bounds__(256) void k_castw(const float* __restrict__ Wuv,
                                               const float* __restrict__ Wo,
                                               unsigned short* __restrict__ Wuvb,
                                               unsigned short* __restrict__ Wob) {
    int i4 = blockIdx.x * 256 + threadIdx.x;   // 0..106495, exact
    const int nuv4 = (N_UV * D_DIM) / 4;       // 73728
    float4 f;
    unsigned short* dst;
    if (i4 < nuv4) { f = ((const float4*)Wuv)[i4]; dst = Wuvb + (size_t)i4 * 4; }
    else { int j = i4 - nuv4; f = ((const float4*)Wo)[j]; dst = Wob + (size_t)j * 4; }
    dst[0] = f2bf(f.x); dst[1] = f2bf(f.y); dst[2] = f2bf(f.z); dst[3] = f2bf(f.w);
}

// ---------------------------------------------------------------------------
// K0: rms-normalize a chunk of tokens, write xn as bf16. One wave per token.
// ---------------------------------------------------------------------------
__global__ __launch_bounds__(256) void k_rms(const float* __restrict__ x,
                                             const float* __restrict__ g,
                                             unsigned short* __restrict__ xn) {
    int wid  = blockIdx.x * 4 + (threadIdx.x >> 6);
    int lane = threadIdx.x & 63;
    float4 vv = ((const float4*)(x + (size_t)wid * D_DIM))[lane];
    float s = vv.x*vv.x + vv.y*vv.y + vv.z*vv.z + vv.w*vv.w;
#pragma unroll
    for (int off = 1; off < 64; off <<= 1) s += __shfl_xor(s, off, 64);
    float sc = g[0] / fmaxf(sqrtf(s) * 0.0625f, EPSF);
    unsigned short o[4] = {f2bf(vv.x*sc), f2bf(vv.y*sc), f2bf(vv.z*sc), f2bf(vv.w*sc)};
    *(ushort4*)(xn + (size_t)wid * D_DIM + lane * 4) = *(const ushort4*)o;
}

// ---------------------------------------------------------------------------
// K1: uv = silu(xn @ Wuv^T) -> u / v / (q,k affine), bf16 MFMA, 64x128 tile.
// grid (133, 9). col0 region is block-uniform (128 | E boundaries).
// ---------------------------------------------------------------------------
__global__ __launch_bounds__(256) void k_gemm1(
    const unsigned short* __restrict__ xn,    // [MROWS][256] bf16
    const unsigned short* __restrict__ Wuvb,  // [1152][256] bf16
    const float* __restrict__ gamma, const float* __restrict__ beta,
    unsigned short* __restrict__ u, unsigned short* __restrict__ v,
    unsigned short* __restrict__ q, unsigned short* __restrict__ kk) {
    __shared__ __align__(16) unsigned short As[64][40];
    __shared__ __align__(16) unsigned short Bs[128][40];
    const int tid = threadIdx.x;
    const int row0 = blockIdx.x * 64;
    const int col0 = blockIdx.y * 128;
    const int w = tid >> 6, lane = tid & 63, m = lane & 15, quad = lane >> 4;
    const int wr = w >> 1, wc = w & 1;
    floatx4 acc[2][4];
#pragma unroll
    for (int i = 0; i < 2; ++i)
#pragma unroll
        for (int j = 0; j < 4; ++j) acc[i][j] = (floatx4){0.f,0.f,0.f,0.f};

    const int ar = tid >> 2, ac8 = (tid & 3) * 8;
    for (int k0 = 0; k0 < D_DIM; k0 += 32) {
        *(short8*)&As[ar][ac8] =
            *(const short8*)(xn + (size_t)(row0 + ar) * D_DIM + k0 + ac8);
        *(short8*)&Bs[ar][ac8] =
            *(const short8*)(Wuvb + (size_t)(col0 + ar) * D_DIM + k0 + ac8);
        *(short8*)&Bs[64 + ar][ac8] =
            *(const short8*)(Wuvb + (size_t)(col0 + 64 + ar) * D_DIM + k0 + ac8);
        __syncthreads();
        short8 a0 = *(const short8*)&As[wr*32 + m][quad*8];
        short8 a1 = *(const short8*)&As[wr*32 + 16 + m][quad*8];
        short8 b0 = *(const short8*)&Bs[wc*64 + m][quad*8];
        short8 b1 = *(const short8*)&Bs[wc*64 + 16 + m][quad*8];
        short8 b2 = *(const short8*)&Bs[wc*64 + 32 + m][quad*8];
        short8 b3 = *(const short8*)&Bs[wc*64 + 48 + m][quad*8];
        acc[0][0] = MFMA16(a0, b0, acc[0][0]);
        acc[0][1] = MFMA16(a0, b1, acc[0][1]);
        acc[0][2] = MFMA16(a0, b2, acc[0][2]);
        acc[0][3] = MFMA16(a0, b3, acc[0][3]);
        acc[1][0] = MFMA16(a1, b0, acc[1][0]);
        acc[1][1] = MFMA16(a1, b1, acc[1][1]);
        acc[1][2] = MFMA16(a1, b2, acc[1][2]);
        acc[1][3] = MFMA16(a1, b3, acc[1][3]);
        __syncthreads();
    }

    const int rbase = row0 + wr*32 + quad*4;
    const int cbase = col0 + wc*64 + m;
#pragma unroll
    for (int it = 0; it < 2; ++it)
#pragma unroll
        for (int jt = 0; jt < 4; ++jt)
#pragma unroll
            for (int r = 0; r < 4; ++r) {
                const int row = rbase + it*16 + r;
                const int col = cbase + jt*16;
                float val = acc[it][jt][r];
                val = val / (1.0f + __expf(-val));   // silu
                if (col0 < E_DIM) {
                    u[(size_t)row * E_DIM + col] = f2bf(val);
                } else if (col0 < 2*E_DIM) {
                    v[(size_t)row * E_DIM + (col - E_DIM)] = f2bf(val);
                } else {
                    const int s = col - 2*E_DIM;
                    q[(size_t)row * S_DIM + s]  = f2bf(fmaf(val, gamma[s],        beta[s]));
                    kk[(size_t)row * S_DIM + s] = f2bf(fmaf(val, gamma[S_DIM+s], beta[S_DIM+s]));
                }
            }
}

// ---------------------------------------------------------------------------
// K2: attention, MFMA. Block = (e-chunk of 128, batch). Stream j-tiles of 64:
// kern_tile = relu(q k^T /sqrt(S))^2 (bf16, LDS) then O += kern_tile @ v_tile.
// q fragments live in registers; v transposed into LDS during staging.
// h = u * O overwrites u (bf16).
// ---------------------------------------------------------------------------
__global__ __launch_bounds__(256) void k_attn(
    const unsigned short* __restrict__ q,
    const unsigned short* __restrict__ kk,
    const unsigned short* __restrict__ v,
    unsigned short* __restrict__ u) {
    __shared__ __align__(16) unsigned short ksh[64][136];   // 17408 B
    __shared__ __align__(16) unsigned short kern[144][72];  // 20736 B
    __shared__ __align__(16) unsigned short vT[128][72];    // 18432 B
    const int tid = threadIdx.x;
    const int ec = blockIdx.x;            // e-chunk 0..3
    const int b  = blockIdx.y;            // batch in chunk
    const int w = tid >> 6, lane = tid & 63, m = lane & 15, quad = lane >> 4;
    const int nit = (w == 0) ? 3 : 2;           // i-tiles per wave (9 total)
    const int itb = (w == 0) ? 0 : (1 + 2*w);   // 0 | 3 | 5 | 7
    const size_t qs0 = (size_t)b * T_SEQ * S_DIM;
    const size_t vs0 = (size_t)b * T_SEQ * E_DIM;

    // preload q fragments (rows >=133 clamped -> finite garbage, never stored)
    short8 qf[3][4];
    for (int t = 0; t < nit; ++t) {
        int ri = (itb + t) * 16 + m;
        if (ri > T_SEQ - 1) ri = T_SEQ - 1;
        const unsigned short* qp = q + qs0 + (size_t)ri * S_DIM + quad * 8;
#pragma unroll
        for (int ks = 0; ks < 4; ++ks)
            qf[t][ks] = *(const short8*)(qp + ks * 32);
    }

    floatx4 oa[3][8];
#pragma unroll
    for (int t = 0; t < 3; ++t)
#pragma unroll
        for (int e = 0; e < 8; ++e) oa[t][e] = (floatx4){0.f,0.f,0.f,0.f};

    const int ve = tid & 127, vh = tid >> 7;
    const short8 z8 = {0,0,0,0,0,0,0,0};

    for (int j0 = 0; j0 < T_SEQ; j0 += 64) {
        // stage k-tile [64][128] (zero-fill rows >= T)
        for (int uu = tid; uu < 1024; uu += 256) {
            int r = uu >> 4, c8 = (uu & 15) * 8;
            short8 val = z8;
            if (j0 + r < T_SEQ)
                val = *(const short8*)(kk + qs0 + (size_t)(j0 + r) * S_DIM + c8);
            *(short8*)&ksh[r][c8] = val;
        }
        // stage v-tile transposed: vT[e][j-local]
        for (int rr = 0; rr < 32; ++rr) {
            int r = vh * 32 + rr;
            unsigned short val = 0;
            if (j0 + r < T_SEQ)
                val = v[vs0 + (size_t)(j0 + r) * E_DIM + ec * 128 + ve];
            vT[ve][r] = val;
        }
        __syncthreads();

        // phase 1: kern rows for this wave's i-tiles
        for (int js = 0; js < 4; ++js) {
            short8 kbf[4];
#pragma unroll
            for (int ks = 0; ks < 4; ++ks)
                kbf[ks] = *(const short8*)&ksh[js*16 + m][ks*32 + quad*8];
            for (int t = 0; t < nit; ++t) {
                floatx4 c = (floatx4){0.f,0.f,0.f,0.f};
#pragma unroll
                for (int ks = 0; ks < 4; ++ks)
                    c = MFMA16(qf[t][ks], kbf[ks], c);
                const int krow = (itb + t) * 16 + quad * 4;
                const int kcol = js * 16 + m;
#pragma unroll
                for (int r = 0; r < 4; ++r) {
                    float sv = c[r] * RSQRT_S;
                    sv = fmaxf(sv, 0.0f);
                    sv *= sv;
                    kern[krow + r][kcol] = f2bf(sv);
                }
            }
        }
        __syncthreads();

        // phase 2: O += kern @ v
        short8 af[3][2];
        for (int t = 0; t < nit; ++t) {
            const int it = itb + t;
            af[t][0] = *(const short8*)&kern[it*16 + m][quad*8];
            af[t][1] = *(const short8*)&kern[it*16 + m][32 + quad*8];
        }
#pragma unroll
        for (int e = 0; e < 8; ++e) {
            short8 bf0 = *(const short8*)&vT[e*16 + m][quad*8];
            short8 bf1 = *(const short8*)&vT[e*16 + m][32 + quad*8];
            for (int t = 0; t < nit; ++t) {
                oa[t][e] = MFMA16(af[t][0], bf0, oa[t][e]);
                oa[t][e] = MFMA16(af[t][1], bf1, oa[t][e]);
            }
        }
        __syncthreads();
    }

    // epilogue: h = u * O (in place, bf16)
    for (int t = 0; t < nit; ++t) {
        const int it = itb + t;
#pragma unroll
        for (int e = 0; e < 8; ++e) {
            const int col = ec * 128 + e * 16 + m;
#pragma unroll
            for (int r = 0; r < 4; ++r) {
                const int row = it * 16 + quad * 4 + r;
                if (row < T_SEQ) {
                    const size_t ad = vs0 + (size_t)row * E_DIM + col;
                    u[ad] = f2bf(bf2f(u[ad]) * oa[t][e][r]);
                }
            }
        }
    }
}

// ---------------------------------------------------------------------------
// K3: out = h @ Wo^T + x*res_scale, bf16 MFMA, 64x64 tile, grid (133, 4).
// ---------------------------------------------------------------------------
__global__ __launch_bounds__(256) void k_gemm2(
    const unsigned short* __restrict__ h,    // [MROWS][512] bf16
    const unsigned short* __restrict__ Wob,  // [256][512] bf16
    const float* __restrict__ x, const float* __restrict__ resS,
    float* __restrict__ out) {
    __shared__ __align__(16) unsigned short As[64][40];
    __shared__ __align__(16) unsigned short Bs[64][40];
    const int tid = threadIdx.x;
    const int row0 = blockIdx.x * 64;
    const int col0 = blockIdx.y * 64;
    const int w = tid >> 6, lane = tid & 63, m = lane & 15, quad = lane >> 4;
    const int wr = w >> 1, wc = w & 1;
    floatx4 acc[2][2];
#pragma unroll
    for (int i = 0; i < 2; ++i)
#pragma unroll
        for (int j = 0; j < 2; ++j) acc[i][j] = (floatx4){0.f,0.f,0.f,0.f};

    const int ar = tid >> 2, ac8 = (tid & 3) * 8;
    for (int k0 = 0; k0 < E_DIM; k0 += 32) {
        *(short8*)&As[ar][ac8] =
            *(const short8*)(h + (size_t)(row0 + ar) * E_DIM + k0 + ac8);
        *(short8*)&Bs[ar][ac8] =
            *(const short8*)(Wob + (size_t)(col0 + ar) * E_DIM + k0 + ac8);
        __syncthreads();
        short8 a0 = *(const short8*)&As[wr*32 + m][quad*8];
        short8 a1 = *(const short8*)&As[wr*32 + 16 + m][quad*8];
        short8 b0 = *(const short8*)&Bs[wc*32 + m][quad*8];
        short8 b1 = *(const short8*)&Bs[wc*32 + 16 + m][quad*8];
        acc[0][0] = MFMA16(a0, b0, acc[0][0]);
        acc[0][1] = MFMA16(a0, b1, acc[0][1]);
        acc[1][0] = MFMA16(a1, b0, acc[1][0]);
        acc[1][1] = MFMA16(a1, b1, acc[1][1]);
        __syncthreads();
    }

    const int rbase = row0 + wr*32 + quad*4;
    const int cbase = col0 + wc*32 + m;
#pragma unroll
    for (int it = 0; it < 2; ++it)
#pragma unroll
        for (int jt = 0; jt < 2; ++jt)
#pragma unroll
            for (int r = 0; r < 4; ++r) {
                const int row = rbase + it*16 + r;
                const int col = cbase + jt*16;
                out[(size_t)row * D_DIM + col] =
                    acc[it][jt][r] + x[(size_t)row * D_DIM + col] * resS[col];
            }
}

// ---------------------------------------------------------------------------
extern "C" void kernel_launch(void* const* d_in, const int* in_sizes, int n_in,
                              void* d_out, int out_size, void* d_ws, size_t ws_size,
                              hipStream_t stream) {
    const float* x     = (const float*)d_in[0];
    const float* Wuv   = (const float*)d_in[1];
    const float* Wo    = (const float*)d_in[2];
    const float* gamma = (const float*)d_in[3];
    const float* beta  = (const float*)d_in[4];
    const float* g     = (const float*)d_in[5];
    const float* resS  = (const float*)d_in[6];
    float* out = (float*)d_out;

    // ws layout (bf16 elements), ~25.8 MB total
    unsigned short* ws   = (unsigned short*)d_ws;
    unsigned short* xn   = ws;                          // MROWS*256
    unsigned short* u    = xn + (size_t)MROWS * D_DIM;  // MROWS*512
    unsigned short* v    = u  + (size_t)MROWS * E_DIM;  // MROWS*512
    unsigned short* qb   = v  + (size_t)MROWS * E_DIM;  // MROWS*128
    unsigned short* kb   = qb + (size_t)MROWS * S_DIM;  // MROWS*128
    unsigned short* Wuvb = kb + (size_t)MROWS * S_DIM;  // 1152*256
    unsigned short* Wob  = Wuvb + (size_t)N_UV * D_DIM; // 256*512

    k_castw<<<416, 256, 0, stream>>>(Wuv, Wo, Wuvb, Wob);

    for (int c = 0; c < B_DIM / CB; ++c) {
        const size_t tok0 = (size_t)c * MROWS;
        k_rms<<<MROWS / 4, 256, 0, stream>>>(x + tok0 * D_DIM, g, xn);
        k_gemm1<<<dim3(133, 9), 256, 0, stream>>>(xn, Wuvb, gamma, beta, u, v, qb, kb);
        k_attn<<<dim3(4, CB), 256, 0, stream>>>(qb, kb, v, u);
        k_gemm2<<<dim3(133, 4), 256, 0, stream>>>(u, Wob, x + tok0 * D_DIM, resS,
                                                  out + tok0 * D_DIM);
    }
}

// Round 3
// 1175.468 us; speedup vs baseline: 6.9213x; 6.9213x over previous
//
#include <hip/hip_runtime.h>
#include <cstdint>
#include <cstddef>

#define D_DIM 256
#define E_DIM 512
#define S_DIM 128
#define B_DIM 1024
#define T_SEQ 133
#define T_PAD 144
#define N_UV 1152
#define NTOK (B_DIM * T_SEQ)
#define CB 64
#define MROWS (CB * T_SEQ)   // 8512 = 133*64
#define EPSF 1e-5f
#define RSQRT_S 0.08838834764831845f

typedef __attribute__((ext_vector_type(8))) short short8;
typedef __attribute__((ext_vector_type(4))) float floatx4;
#define MFMA16(a, b, c) __builtin_amdgcn_mfma_f32_16x16x32_bf16((a), (b), (c), 0, 0, 0)

__device__ __forceinline__ unsigned short f2bf(float f) {
    union { float f; unsigned u; } a; a.f = f;
    unsigned r = a.u + 0x7fffu + ((a.u >> 16) & 1u);
    return (unsigned short)(r >> 16);
}
__device__ __forceinline__ float bf2f(unsigned short h) {
    union { unsigned u; float f; } a; a.u = ((unsigned)h) << 16;
    return a.f;
}

// ---------------------------------------------------------------------------
// Cast weights to bf16 once per launch.
// ---------------------------------------------------------------------------
__global__ __launch_bounds__(256) void k_castw(const float* __restrict__ Wuv,
                                               const float* __restrict__ Wo,
                                               unsigned short* __restrict__ Wuvb,
                                               unsigned short* __restrict__ Wob) {
    int i4 = blockIdx.x * 256 + threadIdx.x;
    const int nuv4 = (N_UV * D_DIM) / 4;
    float4 f;
    unsigned short* dst;
    if (i4 < nuv4) { f = ((const float4*)Wuv)[i4]; dst = Wuvb + (size_t)i4 * 4; }
    else { int j = i4 - nuv4; f = ((const float4*)Wo)[j]; dst = Wob + (size_t)j * 4; }
    dst[0] = f2bf(f.x); dst[1] = f2bf(f.y); dst[2] = f2bf(f.z); dst[3] = f2bf(f.w);
}

// ---------------------------------------------------------------------------
// K0: rms-normalize chunk tokens -> bf16 xn. One wave per token.
// ---------------------------------------------------------------------------
__global__ __launch_bounds__(256) void k_rms(const float* __restrict__ x,
                                             const float* __restrict__ g,
                                             unsigned short* __restrict__ xn) {
    int wid  = blockIdx.x * 4 + (threadIdx.x >> 6);
    int lane = threadIdx.x & 63;
    float4 vv = ((const float4*)(x + (size_t)wid * D_DIM))[lane];
    float s = vv.x*vv.x + vv.y*vv.y + vv.z*vv.z + vv.w*vv.w;
#pragma unroll
    for (int off = 1; off < 64; off <<= 1) s += __shfl_xor(s, off, 64);
    float sc = g[0] / fmaxf(sqrtf(s) * 0.0625f, EPSF);
    unsigned short o[4] = {f2bf(vv.x*sc), f2bf(vv.y*sc), f2bf(vv.z*sc), f2bf(vv.w*sc)};
    *(ushort4*)(xn + (size_t)wid * D_DIM + lane * 4) = *(const ushort4*)o;
}

// ---------------------------------------------------------------------------
// K1: uv = silu(xn @ Wuv^T) -> u / vT (batch-padded transposed) / q,k affine.
// bf16 MFMA, 64x128 tile, grid (133, 9).
// ---------------------------------------------------------------------------
__global__ __launch_bounds__(256) void k_gemm1(
    const unsigned short* __restrict__ xn,    // [MROWS][256]
    const unsigned short* __restrict__ Wuvb,  // [1152][256]
    const float* __restrict__ gamma, const float* __restrict__ beta,
    unsigned short* __restrict__ u,           // [MROWS][512]
    unsigned short* __restrict__ vTg,         // [CB][512][T_PAD]
    unsigned short* __restrict__ q,           // [MROWS][128]
    unsigned short* __restrict__ kk) {        // [MROWS][128]
    __shared__ __align__(16) unsigned short As[64][40];
    __shared__ __align__(16) unsigned short Bs[128][40];
    const int tid = threadIdx.x;
    const int row0 = blockIdx.x * 64;
    const int col0 = blockIdx.y * 128;
    const int w = tid >> 6, lane = tid & 63, m = lane & 15, quad = lane >> 4;
    const int wr = w >> 1, wc = w & 1;
    floatx4 acc[2][4];
#pragma unroll
    for (int i = 0; i < 2; ++i)
#pragma unroll
        for (int j = 0; j < 4; ++j) acc[i][j] = (floatx4){0.f,0.f,0.f,0.f};

    const int ar = tid >> 2, ac8 = (tid & 3) * 8;
    for (int k0 = 0; k0 < D_DIM; k0 += 32) {
        *(short8*)&As[ar][ac8] =
            *(const short8*)(xn + (size_t)(row0 + ar) * D_DIM + k0 + ac8);
        *(short8*)&Bs[ar][ac8] =
            *(const short8*)(Wuvb + (size_t)(col0 + ar) * D_DIM + k0 + ac8);
        *(short8*)&Bs[64 + ar][ac8] =
            *(const short8*)(Wuvb + (size_t)(col0 + 64 + ar) * D_DIM + k0 + ac8);
        __syncthreads();
        short8 a0 = *(const short8*)&As[wr*32 + m][quad*8];
        short8 a1 = *(const short8*)&As[wr*32 + 16 + m][quad*8];
        short8 b0 = *(const short8*)&Bs[wc*64 + m][quad*8];
        short8 b1 = *(const short8*)&Bs[wc*64 + 16 + m][quad*8];
        short8 b2 = *(const short8*)&Bs[wc*64 + 32 + m][quad*8];
        short8 b3 = *(const short8*)&Bs[wc*64 + 48 + m][quad*8];
        acc[0][0] = MFMA16(a0, b0, acc[0][0]);
        acc[0][1] = MFMA16(a0, b1, acc[0][1]);
        acc[0][2] = MFMA16(a0, b2, acc[0][2]);
        acc[0][3] = MFMA16(a0, b3, acc[0][3]);
        acc[1][0] = MFMA16(a1, b0, acc[1][0]);
        acc[1][1] = MFMA16(a1, b1, acc[1][1]);
        acc[1][2] = MFMA16(a1, b2, acc[1][2]);
        acc[1][3] = MFMA16(a1, b3, acc[1][3]);
        __syncthreads();
    }

    const int rbase = row0 + wr*32 + quad*4;
    const int cbase = col0 + wc*64 + m;
#pragma unroll
    for (int it = 0; it < 2; ++it)
#pragma unroll
        for (int jt = 0; jt < 4; ++jt)
#pragma unroll
            for (int r = 0; r < 4; ++r) {
                const int row = rbase + it*16 + r;
                const int col = cbase + jt*16;
                float val = acc[it][jt][r];
                val = val / (1.0f + __expf(-val));   // silu
                if (col0 < E_DIM) {
                    u[(size_t)row * E_DIM + col] = f2bf(val);
                } else if (col0 < 2*E_DIM) {
                    const int e = col - E_DIM;
                    const unsigned bb = (unsigned)row / 133u;
                    const unsigned tt = (unsigned)row - bb * 133u;
                    vTg[(size_t)bb * (E_DIM*T_PAD) + (size_t)e * T_PAD + tt] = f2bf(val);
                } else {
                    const int s = col - 2*E_DIM;
                    q[(size_t)row * S_DIM + s]  = f2bf(fmaf(val, gamma[s],        beta[s]));
                    kk[(size_t)row * S_DIM + s] = f2bf(fmaf(val, gamma[S_DIM+s], beta[S_DIM+s]));
                }
            }
}

// ---------------------------------------------------------------------------
// K2: attention. Grid (12, CB): x = ec(0..3) + 4*ig(0..2), y = batch.
// Block handles 48 q-rows (ig) x 128 e-cols (ec), loops 3 j-tiles of 64.
// Phase1: kern = relu(qk^T/sqrt(S))^2 (bf16 LDS). Phase2: O += kern @ v.
// v comes pre-transposed (vTg). Epilogue: h = u*O staged via LDS, coalesced.
// ---------------------------------------------------------------------------
__global__ __launch_bounds__(256) void k_attn(
    const unsigned short* __restrict__ q,
    const unsigned short* __restrict__ kk,
    const unsigned short* __restrict__ vTg,
    unsigned short* __restrict__ u) {
    __shared__ __align__(16) unsigned short ksh[64][136];  // 17408 B (reused for O)
    __shared__ __align__(16) unsigned short kern[48][72];  //  6912 B
    __shared__ __align__(16) unsigned short vTs[128][72];  // 18432 B
    const int tid = threadIdx.x;
    const int ec = blockIdx.x & 3;
    const int ig = blockIdx.x >> 2;
    const int b  = blockIdx.y;
    const int w = tid >> 6, lane = tid & 63, m = lane & 15, quad = lane >> 4;
    const size_t qs0 = (size_t)b * T_SEQ * S_DIM;
    const size_t us0 = (size_t)b * T_SEQ * E_DIM;
    const unsigned short* vTb = vTg + (size_t)b * E_DIM * T_PAD + (size_t)ec * 128 * T_PAD;

    // preload q fragments for this block's 3 i-tiles (rows clamped; masked at write)
    short8 qf[3][4];
#pragma unroll
    for (int it = 0; it < 3; ++it) {
        int ri = ig * 48 + it * 16 + m;
        if (ri > T_SEQ - 1) ri = T_SEQ - 1;
        const unsigned short* qp = q + qs0 + (size_t)ri * S_DIM + quad * 8;
#pragma unroll
        for (int ks = 0; ks < 4; ++ks) qf[it][ks] = *(const short8*)(qp + ks * 32);
    }

    floatx4 oa[3][2];
#pragma unroll
    for (int it = 0; it < 3; ++it) {
        oa[it][0] = (floatx4){0.f,0.f,0.f,0.f};
        oa[it][1] = (floatx4){0.f,0.f,0.f,0.f};
    }
    const short8 z8 = {0,0,0,0,0,0,0,0};

    for (int j0 = 0; j0 < T_SEQ; j0 += 64) {
        // stage k-tile [64][128], zero rows >= T
        for (int idx = tid; idx < 1024; idx += 256) {
            int r = idx >> 4, c8 = (idx & 15) * 8;
            short8 val = z8;
            if (j0 + r < T_SEQ)
                val = *(const short8*)(kk + qs0 + (size_t)(j0 + r) * S_DIM + c8);
            *(short8*)&ksh[r][c8] = val;
        }
        // stage v-tile (already transposed in global): vTs[e][j]
        for (int idx = tid; idx < 1024; idx += 256) {
            int e = idx >> 3, j8 = idx & 7;
            *(short8*)&vTs[e][j8 * 8] =
                *(const short8*)(vTb + (size_t)e * T_PAD + j0 + j8 * 8);
        }
        __syncthreads();

        // phase 1: wave w computes kern cols [w*16, w*16+16) for all 3 i-tiles
        short8 kbf[4];
#pragma unroll
        for (int ks = 0; ks < 4; ++ks)
            kbf[ks] = *(const short8*)&ksh[w*16 + m][ks*32 + quad*8];
#pragma unroll
        for (int it = 0; it < 3; ++it) {
            floatx4 c = (floatx4){0.f,0.f,0.f,0.f};
#pragma unroll
            for (int ks = 0; ks < 4; ++ks) c = MFMA16(qf[it][ks], kbf[ks], c);
#pragma unroll
            for (int r = 0; r < 4; ++r) {
                float sv = fmaxf(c[r] * RSQRT_S, 0.0f);
                kern[it*16 + quad*4 + r][w*16 + m] = f2bf(sv * sv);
            }
        }
        __syncthreads();

        // phase 2: wave w owns e-frags {2w, 2w+1}; O += kern @ v
#pragma unroll
        for (int ef = 0; ef < 2; ++ef) {
            const int eb = w * 2 + ef;
            short8 b0 = *(const short8*)&vTs[eb*16 + m][quad*8];
            short8 b1 = *(const short8*)&vTs[eb*16 + m][32 + quad*8];
#pragma unroll
            for (int it = 0; it < 3; ++it) {
                short8 a0 = *(const short8*)&kern[it*16 + m][quad*8];
                short8 a1 = *(const short8*)&kern[it*16 + m][32 + quad*8];
                oa[it][ef] = MFMA16(a0, b0, oa[it][ef]);
                oa[it][ef] = MFMA16(a1, b1, oa[it][ef]);
            }
        }
        __syncthreads();
    }

    // stage O into LDS (reuse ksh as [48][136])
#pragma unroll
    for (int it = 0; it < 3; ++it)
#pragma unroll
        for (int ef = 0; ef < 2; ++ef) {
            const int eb = w * 2 + ef;
#pragma unroll
            for (int r = 0; r < 4; ++r)
                ksh[it*16 + quad*4 + r][eb*16 + m] = f2bf(oa[it][ef][r]);
        }
    __syncthreads();

    // h = u * O, coalesced 16B rows
    for (int idx = tid; idx < 48 * 16; idx += 256) {
        const int rl = idx >> 4, c8 = (idx & 15) * 8;
        const int grow = ig * 48 + rl;
        if (grow < T_SEQ) {
            const size_t ad = us0 + (size_t)grow * E_DIM + ec * 128 + c8;
            short8 uv = *(const short8*)(u + ad);
            unsigned short hv[8];
#pragma unroll
            for (int i = 0; i < 8; ++i)
                hv[i] = f2bf(bf2f((unsigned short)uv[i]) * bf2f(ksh[rl][c8 + i]));
            *(short8*)(u + ad) = *(const short8*)hv;
        }
    }
}

// ---------------------------------------------------------------------------
// K3: out = h @ Wo^T + x*res_scale, bf16 MFMA, 64x64 tile, grid (133, 4).
// ---------------------------------------------------------------------------
__global__ __launch_bounds__(256) void k_gemm2(
    const unsigned short* __restrict__ h,
    const unsigned short* __restrict__ Wob,
    const float* __restrict__ x, const float* __restrict__ resS,
    float* __restrict__ out) {
    __shared__ __align__(16) unsigned short As[64][40];
    __shared__ __align__(16) unsigned short Bs[64][40];
    const int tid = threadIdx.x;
    const int row0 = blockIdx.x * 64;
    const int col0 = blockIdx.y * 64;
    const int w = tid >> 6, lane = tid & 63, m = lane & 15, quad = lane >> 4;
    const int wr = w >> 1, wc = w & 1;
    floatx4 acc[2][2];
#pragma unroll
    for (int i = 0; i < 2; ++i)
#pragma unroll
        for (int j = 0; j < 2; ++j) acc[i][j] = (floatx4){0.f,0.f,0.f,0.f};

    const int ar = tid >> 2, ac8 = (tid & 3) * 8;
    for (int k0 = 0; k0 < E_DIM; k0 += 32) {
        *(short8*)&As[ar][ac8] =
            *(const short8*)(h + (size_t)(row0 + ar) * E_DIM + k0 + ac8);
        *(short8*)&Bs[ar][ac8] =
            *(const short8*)(Wob + (size_t)(col0 + ar) * E_DIM + k0 + ac8);
        __syncthreads();
        short8 a0 = *(const short8*)&As[wr*32 + m][quad*8];
        short8 a1 = *(const short8*)&As[wr*32 + 16 + m][quad*8];
        short8 b0 = *(const short8*)&Bs[wc*32 + m][quad*8];
        short8 b1 = *(const short8*)&Bs[wc*32 + 16 + m][quad*8];
        acc[0][0] = MFMA16(a0, b0, acc[0][0]);
        acc[0][1] = MFMA16(a0, b1, acc[0][1]);
        acc[1][0] = MFMA16(a1, b0, acc[1][0]);
        acc[1][1] = MFMA16(a1, b1, acc[1][1]);
        __syncthreads();
    }

    const int rbase = row0 + wr*32 + quad*4;
    const int cbase = col0 + wc*32 + m;
#pragma unroll
    for (int it = 0; it < 2; ++it)
#pragma unroll
        for (int jt = 0; jt < 2; ++jt)
#pragma unroll
            for (int r = 0; r < 4; ++r) {
                const int row = rbase + it*16 + r;
                const int col = cbase + jt*16;
                out[(size_t)row * D_DIM + col] =
                    acc[it][jt][r] + x[(size_t)row * D_DIM + col] * resS[col];
            }
}

// ---------------------------------------------------------------------------
extern "C" void kernel_launch(void* const* d_in, const int* in_sizes, int n_in,
                              void* d_out, int out_size, void* d_ws, size_t ws_size,
                              hipStream_t stream) {
    const float* x     = (const float*)d_in[0];
    const float* Wuv   = (const float*)d_in[1];
    const float* Wo    = (const float*)d_in[2];
    const float* gamma = (const float*)d_in[3];
    const float* beta  = (const float*)d_in[4];
    const float* g     = (const float*)d_in[5];
    const float* resS  = (const float*)d_in[6];
    float* out = (float*)d_out;

    // ws layout (bf16 elements), ~37 MB total
    unsigned short* ws   = (unsigned short*)d_ws;
    unsigned short* xn   = ws;                            // MROWS*256
    unsigned short* u    = xn + (size_t)MROWS * D_DIM;    // MROWS*512
    unsigned short* vTg  = u  + (size_t)MROWS * E_DIM;    // CB*512*T_PAD
    unsigned short* qb   = vTg + (size_t)CB * E_DIM * T_PAD; // MROWS*128
    unsigned short* kb   = qb + (size_t)MROWS * S_DIM;    // MROWS*128
    unsigned short* Wuvb = kb + (size_t)MROWS * S_DIM;    // 1152*256
    unsigned short* Wob  = Wuvb + (size_t)N_UV * D_DIM;   // 256*512

    k_castw<<<416, 256, 0, stream>>>(Wuv, Wo, Wuvb, Wob);

    for (int c = 0; c < B_DIM / CB; ++c) {
        const size_t tok0 = (size_t)c * MROWS;
        k_rms<<<MROWS / 4, 256, 0, stream>>>(x + tok0 * D_DIM, g, xn);
        k_gemm1<<<dim3(133, 9), 256, 0, stream>>>(xn, Wuvb, gamma, beta, u, vTg, qb, kb);
        k_attn<<<dim3(12, CB), 256, 0, stream>>>(qb, kb, vTg, u);
        k_gemm2<<<dim3(133, 4), 256, 0, stream>>>(u, Wob, x + tok0 * D_DIM, resS,
                                                  out + tok0 * D_DIM);
    }
}